// Round 6
// baseline (135.908 us; speedup 1.0000x reference)
//
// Flash-attention SDPA (GQA 16:4), MI355X gfx950.
// fp32 q in, fp32 out; K/V pre-converted to bf16 in d_ws (prologue);
// XCD-local block mapping (g%8) keeps K/V L2-resident.
// S^T = K*Q^T keeps P in registers; max-free softmax; ones-MFMA row-sum.
// V stays in LDS (R1/R2: V-from-L2 gather = 16 segments/instr -> 145 us).
// This revision: SPLIT-K WAVES. R4 (2 waves/SIMD, 32 q/wave) = 61.4 us
// TLP-starved; R5 (4 waves/SIMD, 16 q/wave) = 59.4 us flat because each
// wave reads the FULL K/V tile -> LDS reads doubled to 8 MB/CU-pass
// (~77% of wall at 85 B/cyc/CU). Invariant: LDS bytes = waves/CU x 512KB
// / (q-rows/wave ratio); TLP and LDS amortization conflict on the q axis
// -- but not on the KEY axis. 8 waves = 4 q-band-pairs x 2 key-halves:
// each wave does 32 q x 64 keys per tile, reads HALF the tile (16 KB).
// LDS back to 4 MB/CU-pass (R4 level) at 4 waves/SIMD (R5 level).
// Max-free softmax makes split-K linear: partial O / rowsum just add in
// an LDS merge epilogue (scalar b32, lane-consecutive, conflict-free).
#include <hip/hip_runtime.h>
#include <hip/hip_bf16.h>

typedef unsigned short u16;
typedef short s16x4 __attribute__((ext_vector_type(4)));
typedef short s16x8 __attribute__((ext_vector_type(8)));
typedef float fx4 __attribute__((ext_vector_type(4)));
typedef unsigned ux2 __attribute__((ext_vector_type(2)));

#define BATCH 2
#define NHQ 16
#define NHKV 4
#define SEQ 2048
#define HD 64
#define TM 128
#define TN 128
#define NTILES (SEQ / TN)
#define VSTRIDE 132   // u16 row stride of shVt (66 dwords == 2 mod 32)
#define NKV (BATCH * NHKV * SEQ * HD)   // 1,048,576 elems per tensor
// (1/sqrt(HD)) * log2(e)
#define QSCALE 0.18033688011112042f

// {lo16: bf16(a), hi16: bf16(b)}, round-half-up (+0x8000) then byte-perm.
__device__ __forceinline__ unsigned pack2_bf16(float a, float b) {
    const unsigned ua = __float_as_uint(a) + 0x8000u;
    const unsigned ub = __float_as_uint(b) + 0x8000u;
    return __builtin_amdgcn_perm(ub, ua, 0x07060302u);
}
// interleave low/high u16 halves of two dwords (row0, row1 of V)
__device__ __forceinline__ unsigned ilv_lo(unsigned r0, unsigned r1) {
    return __builtin_amdgcn_perm(r1, r0, 0x05040100u);
}
__device__ __forceinline__ unsigned ilv_hi(unsigned r0, unsigned r1) {
    return __builtin_amdgcn_perm(r1, r0, 0x07060302u);
}

// Prologue: K,V fp32 -> bf16 into workspace. 1024 blocks x 256 thr x 4 elems.
__global__ __launch_bounds__(256) void cvt_kv_kernel(
    const float* __restrict__ K, const float* __restrict__ V,
    u16* __restrict__ wsK, u16* __restrict__ wsV)
{
    const int i = (blockIdx.x * 256 + threadIdx.x) * 4;
    const fx4 k4 = *(const fx4*)(K + i);
    const fx4 v4 = *(const fx4*)(V + i);
    ux2 ko, vo;
    ko[0] = pack2_bf16(k4[0], k4[1]);
    ko[1] = pack2_bf16(k4[2], k4[3]);
    vo[0] = pack2_bf16(v4[0], v4[1]);
    vo[1] = pack2_bf16(v4[2], v4[3]);
    *(ux2*)(wsK + i) = ko;
    *(ux2*)(wsV + i) = vo;
}

__global__ __launch_bounds__(512, 4) void ptSDPA_39668317946373_kernel(
    const float* __restrict__ gQ,
    const u16* __restrict__ wsK,
    const u16* __restrict__ wsV,
    float* __restrict__ gO)
{
    // Double-buffered tiles: 2 x (16 + 16.5) KB = 65 KB -> 2 blocks/CU.
    __shared__ u16 shK[2][TN * HD];        // [buf][key][d], XOR-chunk swizzle
    __shared__ u16 shVt[2][HD * VSTRIDE];  // [buf][d][key], padded stride

    const int tid = threadIdx.x;
    const int wv  = tid >> 6;       // 0..7
    const int qw  = wv & 3;         // q-band-pair 0..3 (32 rows each)
    const int kh  = wv >> 2;        // key-half 0..1 (64 keys per tile)
    const int ln  = tid & 63;
    const int l15 = ln & 15;
    const int qd  = ln >> 4;        // quad 0..3

    // XCD-local decode: g%8 = kv-group (= batch*NHKV + hkv).
    const int g     = blockIdx.x;
    const int kvg   = g & 7;
    const int inner = g >> 3;        // 0..63
    const int qtb   = inner & 15;
    const int hqw   = inner >> 4;    // 0..3
    const int batch = kvg >> 2;
    const int hkv   = kvg & 3;
    const int head  = batch * NHQ + hkv * 4 + hqw;

    // De-phase: co-resident blocks start their tile loop at different
    // rotations so their compute phases decorrelate.
    const int t0 = (inner & 3) * 4;

    const float* q_base = gQ + (size_t)head * SEQ * HD;
    const u16*   k_base = wsK + (size_t)kvg * SEQ * HD;
    const u16*   v_base = wsV + (size_t)kvg * SEQ * HD;
    float*       o_base = gO + (size_t)head * SEQ * HD;

    const int qrow0 = qtb * TM;

    // Q fragments (B-operand of S^T MFMA: lane&15 = q, k = quad*8+j),
    // pre-scaled by QSCALE. Two bands mi = 0,1 per wave (rows qw*32+mi*16).
    s16x8 qfrag[2][2];
#pragma unroll
    for (int mi = 0; mi < 2; mi++) {
        const int row = qrow0 + qw * 32 + mi * 16 + l15;
#pragma unroll
        for (int ks = 0; ks < 2; ks++) {
            const int d0 = ks * 32 + qd * 8;
            const fx4 lo = *(const fx4*)(q_base + (size_t)row * HD + d0);
            const fx4 hi = *(const fx4*)(q_base + (size_t)row * HD + d0 + 4);
            union { unsigned u[4]; s16x8 v; } t;
            t.u[0] = pack2_bf16(lo[0] * QSCALE, lo[1] * QSCALE);
            t.u[1] = pack2_bf16(lo[2] * QSCALE, lo[3] * QSCALE);
            t.u[2] = pack2_bf16(hi[0] * QSCALE, hi[1] * QSCALE);
            t.u[3] = pack2_bf16(hi[2] * QSCALE, hi[3] * QSCALE);
            qfrag[mi][ks] = t.v;
        }
    }

    // O accumulators (C layout: col = d, row = q) + row-sum accumulators.
    // Partial over this wave's key-half; merged across kh in the epilogue.
    fx4 oacc[2][4];
    fx4 racc[2];
    const fx4 z4 = {0.f, 0.f, 0.f, 0.f};
#pragma unroll
    for (int mi = 0; mi < 2; mi++) {
        racc[mi] = z4;
#pragma unroll
        for (int ni = 0; ni < 4; ni++) oacc[mi][ni] = z4;
    }
    // B-operand of the row-sum MFMA: all-ones bf16.
    const s16x4 ones4 = {(short)0x3F80, (short)0x3F80,
                         (short)0x3F80, (short)0x3F80};

    // Staging split by wave group (wave-uniform branch):
    //  waves 0-3 (tid 0..255):   V stager — key pair 2*st over 16 d band.
    //  waves 4-7 (tid 256..511): K stager — one key row, half the head dim.
    const bool isV = (wv < 4);
    const int  st  = isV ? tid : (tid - 256);
    // V-stager params
    const int vkey = (st & 63) * 2;
    const int vd0  = (st >> 6) * 16;
    const u16* vp0 = v_base + vkey * HD + vd0;
    // K-stager params
    const int skey  = st & 127;
    const int shalf = st >> 7;
    const u16* kp0 = k_base + skey * HD + shalf * 32;

    s16x8 preg[4];   // 16 VGPRs of prefetch state (K or V role)

    // First tile (t0): load then stage into buffer 0.
    if (isV) {
        const u16* vp = vp0 + (size_t)t0 * TN * HD;
        preg[0] = *(const s16x8*)(vp);
        preg[1] = *(const s16x8*)(vp + 8);
        preg[2] = *(const s16x8*)(vp + HD);
        preg[3] = *(const s16x8*)(vp + HD + 8);
#pragma unroll
        for (int h = 0; h < 2; h++) {
            union { s16x8 v; unsigned u[4]; } r0, r1;
            r0.v = preg[h];
            r1.v = preg[2 + h];
#pragma unroll
            for (int c2 = 0; c2 < 4; c2++) {
                const int d = vd0 + h * 8 + c2 * 2;
                *(unsigned*)(shVt[0] + d * VSTRIDE + vkey) =
                    ilv_lo(r0.u[c2], r1.u[c2]);
                *(unsigned*)(shVt[0] + (d + 1) * VSTRIDE + vkey) =
                    ilv_hi(r0.u[c2], r1.u[c2]);
            }
        }
    } else {
#pragma unroll
        for (int s = 0; s < 4; s++)
            preg[s] = *(const s16x8*)(kp0 + (size_t)t0 * TN * HD + s * 8);
#pragma unroll
        for (int s = 0; s < 4; s++) {
            const int c = shalf * 4 + s;
            *(s16x8*)(shK[0] + skey * 64 + ((c ^ (skey & 7)) * 8)) = preg[s];
        }
    }

    const int ktbase = kh * 4;   // this wave's 4 kt slots (64 keys)

#pragma unroll 2
    for (int i = 0; i < NTILES; i++) {
        const int cur = i & 1;
        const int nxt = cur ^ 1;

        // Single barrier per tile: buf[cur] staged AND buf[nxt] readers done.
        __syncthreads();

        // Prefetch the next tile in this block's rotated order.
        if (i + 1 < NTILES) {
            const int tp = (t0 + i + 1) & (NTILES - 1);
            if (isV) {
                const u16* vp = vp0 + (size_t)tp * TN * HD;
                preg[0] = *(const s16x8*)(vp);
                preg[1] = *(const s16x8*)(vp + 8);
                preg[2] = *(const s16x8*)(vp + HD);
                preg[3] = *(const s16x8*)(vp + HD + 8);
            } else {
                const u16* kp = kp0 + (size_t)tp * TN * HD;
#pragma unroll
                for (int s = 0; s < 4; s++)
                    preg[s] = *(const s16x8*)(kp + s * 8);
            }
        }

        // Fused per-kt pipeline over THIS WAVE'S key-half (4 kt slots),
        // skew-1: QK(kt+1) in flight while exp2/pack(kt) runs on the VALU,
        // then PV(kt) on the matrix pipe.
        const int kb7 = l15 & 7;
        const int sw0 = (qd ^ kb7) << 3;          // ks=0 chunk swizzle
        const int sw1 = ((4 + qd) ^ kb7) << 3;    // ks=1 chunk swizzle
        const u16* kRow = shK[cur] + l15 * 64;

        fx4 scp[2][2];   // [kt&1][mi]
        {   // QK(ktbase)
            const s16x8 kf0 = *(const s16x8*)(kRow + ktbase * 1024 + sw0);
            const s16x8 kf1 = *(const s16x8*)(kRow + ktbase * 1024 + sw1);
#pragma unroll
            for (int mi = 0; mi < 2; mi++)
                scp[0][mi] = __builtin_amdgcn_mfma_f32_16x16x32_bf16(
                    kf0, qfrag[mi][0], z4, 0, 0, 0);
#pragma unroll
            for (int mi = 0; mi < 2; mi++)
                scp[0][mi] = __builtin_amdgcn_mfma_f32_16x16x32_bf16(
                    kf1, qfrag[mi][1], scp[0][mi], 0, 0, 0);
        }

#pragma unroll
        for (int kt = 0; kt < 4; kt++) {
            const int p = kt & 1;
            if (kt < 3) {   // QK(ktbase+kt+1)
                const s16x8 kf0 =
                    *(const s16x8*)(kRow + (ktbase + kt + 1) * 1024 + sw0);
                const s16x8 kf1 =
                    *(const s16x8*)(kRow + (ktbase + kt + 1) * 1024 + sw1);
#pragma unroll
                for (int mi = 0; mi < 2; mi++)
                    scp[p ^ 1][mi] = __builtin_amdgcn_mfma_f32_16x16x32_bf16(
                        kf0, qfrag[mi][0], z4, 0, 0, 0);
#pragma unroll
                for (int mi = 0; mi < 2; mi++)
                    scp[p ^ 1][mi] = __builtin_amdgcn_mfma_f32_16x16x32_bf16(
                        kf1, qfrag[mi][1], scp[p ^ 1][mi], 0, 0, 0);
            }

            // V fragments for kt (in flight during exp2/pack below).
            // dword = 66*d + key/2: conflict-free (measured 0).
            const int kb = (ktbase + kt) * 16 + qd * 4;
            s16x4 vf[4];
#pragma unroll
            for (int ni = 0; ni < 4; ni++)
                vf[ni] = *(const s16x4*)(
                    shVt[cur] + (ni * 16 + l15) * VSTRIDE + kb);

            // exp2 in-register; pack into PV A-fragments (lane&15 = q,
            // k = quad*4+j == the S^T C layout).
            s16x4 pf[2];
#pragma unroll
            for (int mi = 0; mi < 2; mi++) {
                const float p0 = __builtin_amdgcn_exp2f(scp[p][mi][0]);
                const float p1 = __builtin_amdgcn_exp2f(scp[p][mi][1]);
                const float p2 = __builtin_amdgcn_exp2f(scp[p][mi][2]);
                const float p3 = __builtin_amdgcn_exp2f(scp[p][mi][3]);
                union { unsigned u[2]; s16x4 v; } pp;
                pp.u[0] = pack2_bf16(p0, p1);
                pp.u[1] = pack2_bf16(p2, p3);
                pf[mi] = pp.v;
            }

            // Row sums on the matrix pipe (partial over this key-half).
#pragma unroll
            for (int mi = 0; mi < 2; mi++)
                racc[mi] = __builtin_amdgcn_mfma_f32_16x16x16bf16_1k(
                    pf[mi], ones4, racc[mi], 0, 0, 0);

            // O += P V as K=16 MFMAs.
#pragma unroll
            for (int ni = 0; ni < 4; ni++) {
#pragma unroll
                for (int mi = 0; mi < 2; mi++)
                    oacc[mi][ni] = __builtin_amdgcn_mfma_f32_16x16x16bf16_1k(
                        pf[mi], vf[ni], oacc[mi][ni], 0, 0, 0);
            }
        }

        // Stage prefetched tile into the other buffer (no barrier: buf[nxt]
        // is not read until after the next loop-top barrier).
        if (i + 1 < NTILES) {
            if (isV) {
#pragma unroll
                for (int h = 0; h < 2; h++) {
                    union { s16x8 v; unsigned u[4]; } r0, r1;
                    r0.v = preg[h];
                    r1.v = preg[2 + h];
#pragma unroll
                    for (int c2 = 0; c2 < 4; c2++) {
                        const int d = vd0 + h * 8 + c2 * 2;
                        *(unsigned*)(shVt[nxt] + d * VSTRIDE + vkey) =
                            ilv_lo(r0.u[c2], r1.u[c2]);
                        *(unsigned*)(shVt[nxt] + (d + 1) * VSTRIDE + vkey) =
                            ilv_hi(r0.u[c2], r1.u[c2]);
                    }
                }
            } else {
#pragma unroll
                for (int s = 0; s < 4; s++) {
                    const int c = shalf * 4 + s;
                    *(s16x8*)(shK[nxt] + skey * 64 + ((c ^ (skey & 7)) * 8)) =
                        preg[s];
                }
            }
        }
    }

    // ---- Split-K merge epilogue (max-free softmax => linear merge) ----
    // Waves 4-7 (key-half 1) dump partial oacc/racc to LDS; waves 0-3 add
    // their partner's partials, normalize, store. Scalar b32 at
    // lane-consecutive addresses: 2 lanes/bank = conflict-free (m136).
    __syncthreads();   // all waves done reading shK/shVt buffers
    float* mo = (float*)&shK[0][0];    // 32 regs x 256 slots = 32 KB exact
    float* mr = (float*)&shVt[0][0];   // 8 regs x 256 slots = 8 KB
    if (kh == 1) {
        const int slot = qw * 64 + ln;
#pragma unroll
        for (int mi = 0; mi < 2; mi++) {
#pragma unroll
            for (int ni = 0; ni < 4; ni++)
#pragma unroll
                for (int r = 0; r < 4; r++)
                    mo[((mi * 4 + ni) * 4 + r) * 256 + slot] = oacc[mi][ni][r];
#pragma unroll
            for (int r = 0; r < 4; r++)
                mr[(mi * 4 + r) * 256 + slot] = racc[mi][r];
        }
    }
    __syncthreads();
    if (kh == 0) {
        const int slot = qw * 64 + ln;
#pragma unroll
        for (int mi = 0; mi < 2; mi++) {
#pragma unroll
            for (int ni = 0; ni < 4; ni++)
#pragma unroll
                for (int r = 0; r < 4; r++)
                    oacc[mi][ni][r] += mo[((mi * 4 + ni) * 4 + r) * 256 + slot];
#pragma unroll
            for (int r = 0; r < 4; r++)
                racc[mi][r] += mr[(mi * 4 + r) * 256 + slot];
        }
        // Normalize, store fp32 (racc holds full row sums, q = qd*4+r).
#pragma unroll
        for (int mi = 0; mi < 2; mi++) {
            float inv[4];
#pragma unroll
            for (int r = 0; r < 4; r++) inv[r] = 1.0f / racc[mi][r];
#pragma unroll
            for (int ni = 0; ni < 4; ni++)
#pragma unroll
                for (int r = 0; r < 4; r++) {
                    const int qr = qrow0 + qw * 32 + mi * 16 + qd * 4 + r;
                    o_base[(size_t)qr * HD + ni * 16 + l15] =
                        oacc[mi][ni][r] * inv[r];
                }
        }
    }
}

extern "C" void kernel_launch(void* const* d_in, const int* in_sizes, int n_in,
                              void* d_out, int out_size, void* d_ws, size_t ws_size,
                              hipStream_t stream) {
    const float* q = (const float*)d_in[0];
    const float* k = (const float*)d_in[1];
    const float* v = (const float*)d_in[2];
    float*       o = (float*)d_out;
    u16* wsK = (u16*)d_ws;            // 2 MB
    u16* wsV = wsK + NKV;             // 2 MB  (4 MB total workspace)
    cvt_kv_kernel<<<NKV / 1024, 256, 0, stream>>>(k, v, wsK, wsV);
    const dim3 grid(BATCH * NHQ * (SEQ / TM));   // 512 workgroups, 512 thr
    ptSDPA_39668317946373_kernel<<<grid, 512, 0, stream>>>(q, wsK, wsV, o);
}